// Round 1
// baseline (185.504 us; speedup 1.0000x reference)
//
#include <hip/hip_runtime.h>

typedef short s16x8 __attribute__((ext_vector_type(8)));
typedef float f32x4 __attribute__((ext_vector_type(4)));

#define MFMA(a, b, c) __builtin_amdgcn_mfma_f32_16x16x32_bf16(a, b, c, 0, 0, 0)

__device__ __forceinline__ unsigned short f2bf(float f) {
  unsigned int u = __builtin_bit_cast(unsigned int, f);
  u += 0x7FFFu + ((u >> 16) & 1u);
  return (unsigned short)(u >> 16);
}

// ---------- kernel 1: W [1024][64] fp32 -> Wt [3][64][1024] bf16 ----------
__global__ __launch_bounds__(256) void wt_kernel(const float* __restrict__ Wq,
                                                 const float* __restrict__ Wk,
                                                 const float* __restrict__ Wv,
                                                 unsigned short* __restrict__ Wt) {
  int i = blockIdx.x * 256 + threadIdx.x;  // 3*64*1024 = 196608 total
  int m = i >> 16;
  int rem = i & 65535;
  int h = rem >> 10;
  int c = rem & 1023;
  const float* W = (m == 0) ? Wq : (m == 1) ? Wk : Wv;
  Wt[i] = f2bf(W[c * 64 + h]);
}

// ---------- kernel 2: projection x @ {Wq,Wk,Wv} -> q,k (row-major bf16), vt (transposed bf16) ----------
__global__ __launch_bounds__(256) void proj_kernel(const float* __restrict__ x,
                                                   const unsigned short* __restrict__ Wt,
                                                   unsigned short* __restrict__ qm,
                                                   unsigned short* __restrict__ km,
                                                   unsigned short* __restrict__ vt) {
  int lane = threadIdx.x & 63;
  int wv = threadIdx.x >> 6;
  int gw = blockIdx.x * 4 + wv;
  int row0 = gw * 16;
  int c = lane & 15, g = lane >> 4;
  const float* xp = x + (size_t)(row0 + c) * 1024 + 8 * g;

  f32x4 acc[3][4];
#pragma unroll
  for (int m = 0; m < 3; ++m)
#pragma unroll
    for (int n = 0; n < 4; ++n) acc[m][n] = (f32x4){0.f, 0.f, 0.f, 0.f};

  for (int k0 = 0; k0 < 1024; k0 += 32) {
    const float4* ap = (const float4*)(xp + k0);
    float4 a0 = ap[0], a1 = ap[1];
    s16x8 af;
    af[0] = (short)f2bf(a0.x); af[1] = (short)f2bf(a0.y);
    af[2] = (short)f2bf(a0.z); af[3] = (short)f2bf(a0.w);
    af[4] = (short)f2bf(a1.x); af[5] = (short)f2bf(a1.y);
    af[6] = (short)f2bf(a1.z); af[7] = (short)f2bf(a1.w);
#pragma unroll
    for (int m = 0; m < 3; ++m) {
#pragma unroll
      for (int n = 0; n < 4; ++n) {
        s16x8 bf = *(const s16x8*)(Wt + (size_t)(m * 64 + 16 * n + c) * 1024 + k0 + 8 * g);
        acc[m][n] = MFMA(af, bf, acc[m][n]);
      }
    }
  }

  int b = row0 >> 12;
#pragma unroll
  for (int m = 0; m < 3; ++m) {
#pragma unroll
    for (int n = 0; n < 4; ++n) {
#pragma unroll
      for (int r = 0; r < 4; ++r) {
        unsigned short hv = f2bf(acc[m][n][r]);
        int row = row0 + 4 * g + r;
        int col = 16 * n + c;
        if (m == 0) qm[(size_t)row * 64 + col] = hv;
        else if (m == 1) km[(size_t)row * 64 + col] = hv;
        else vt[((size_t)b * 64 + col) * 4096 + (row & 4095)] = hv;
      }
    }
  }
}

// ---------- kernel 3: flash attention ----------
// block = 4 waves; each block owns one 16-row Q tile; waves split KV tiles strided;
// online-softmax partials merged through LDS at the end.
__global__ __launch_bounds__(256) void attn_kernel(const unsigned short* __restrict__ qm,
                                                   const unsigned short* __restrict__ km,
                                                   const unsigned short* __restrict__ vt,
                                                   float* __restrict__ out) {
  __shared__ __align__(16) unsigned short Plds[4][16][32];
  __shared__ float Olds[4][16][64];
  __shared__ float mlds[4][16];
  __shared__ float llds[4][16];

  int tid = threadIdx.x;
  int lane = tid & 63, wv = tid >> 6;
  int c = lane & 15, g = lane >> 4;
  int bid = blockIdx.x;
  int b = bid & 3;
  int j = 255 - (bid >> 2);  // big tiles dispatched first
  int q0 = j * 16;
  int qlast = q0 + 15;
  const float SC = 0.1803368801111204f;  // (1/sqrt(64)) * log2(e)

  const unsigned short* qb = qm + ((size_t)b * 4096 + q0) * 64;
  s16x8 qf0 = *(const s16x8*)(qb + (size_t)c * 64 + 8 * g);
  s16x8 qf1 = *(const s16x8*)(qb + (size_t)c * 64 + 32 + 8 * g);

  f32x4 of[4];
#pragma unroll
  for (int d = 0; d < 4; ++d) of[d] = (f32x4){0.f, 0.f, 0.f, 0.f};
  float mrow[4] = {-1e30f, -1e30f, -1e30f, -1e30f};
  float lpart[4] = {0.f, 0.f, 0.f, 0.f};

  const unsigned short* kbb = km + (size_t)b * 4096 * 64;
  const unsigned short* vbb = vt + (size_t)b * 64 * 4096;

  for (int kv0 = wv * 32; kv0 <= qlast; kv0 += 128) {
    const unsigned short* kb = kbb + (size_t)kv0 * 64;
    s16x8 kf00 = *(const s16x8*)(kb + c * 64 + 8 * g);
    s16x8 kf01 = *(const s16x8*)(kb + c * 64 + 32 + 8 * g);
    s16x8 kf10 = *(const s16x8*)(kb + (16 + c) * 64 + 8 * g);
    s16x8 kf11 = *(const s16x8*)(kb + (16 + c) * 64 + 32 + 8 * g);

    f32x4 s0 = (f32x4){0.f, 0.f, 0.f, 0.f};
    f32x4 s1 = (f32x4){0.f, 0.f, 0.f, 0.f};
    s0 = MFMA(qf0, kf00, s0);
    s0 = MFMA(qf1, kf01, s0);
    s1 = MFMA(qf0, kf10, s1);
    s1 = MFMA(qf1, kf11, s1);

    float sv0[4], sv1[4], tm[4];
#pragma unroll
    for (int r = 0; r < 4; ++r) {
      int qr = q0 + 4 * g + r;
      float v0 = s0[r] * SC;
      if (kv0 + c > qr) v0 = -1e30f;
      float v1 = s1[r] * SC;
      if (kv0 + 16 + c > qr) v1 = -1e30f;
      sv0[r] = v0;
      sv1[r] = v1;
      tm[r] = fmaxf(v0, v1);
    }
#pragma unroll
    for (int msk = 1; msk <= 8; msk <<= 1) {
#pragma unroll
      for (int r = 0; r < 4; ++r) tm[r] = fmaxf(tm[r], __shfl_xor(tm[r], msk));
    }
    float p0[4], p1[4];
#pragma unroll
    for (int r = 0; r < 4; ++r) {
      float nm = fmaxf(mrow[r], tm[r]);
      float al = exp2f(mrow[r] - nm);
      mrow[r] = nm;
      p0[r] = exp2f(sv0[r] - nm);
      p1[r] = exp2f(sv1[r] - nm);
      lpart[r] = lpart[r] * al + p0[r] + p1[r];
      of[0][r] *= al;
      of[1][r] *= al;
      of[2][r] *= al;
      of[3][r] *= al;
    }
    // P -> LDS (S-layout) -> A-fragment layout
#pragma unroll
    for (int r = 0; r < 4; ++r) {
      Plds[wv][4 * g + r][c] = f2bf(p0[r]);
      Plds[wv][4 * g + r][16 + c] = f2bf(p1[r]);
    }
    s16x8 pf = *(const s16x8*)(&Plds[wv][c][8 * g]);
#pragma unroll
    for (int dt = 0; dt < 4; ++dt) {
      s16x8 vf = *(const s16x8*)(vbb + (size_t)(16 * dt + c) * 4096 + kv0 + 8 * g);
      of[dt] = MFMA(pf, vf, of[dt]);
    }
  }

  // ---- merge 4 wave-partials ----
  float lsum[4] = {lpart[0], lpart[1], lpart[2], lpart[3]};
#pragma unroll
  for (int msk = 1; msk <= 8; msk <<= 1) {
#pragma unroll
    for (int r = 0; r < 4; ++r) lsum[r] += __shfl_xor(lsum[r], msk);
  }
  if (c == 0) {
#pragma unroll
    for (int r = 0; r < 4; ++r) {
      mlds[wv][4 * g + r] = mrow[r];
      llds[wv][4 * g + r] = lsum[r];
    }
  }
#pragma unroll
  for (int dt = 0; dt < 4; ++dt)
#pragma unroll
    for (int r = 0; r < 4; ++r) Olds[wv][4 * g + r][16 * dt + c] = of[dt][r];
  __syncthreads();

#pragma unroll
  for (int ii = 0; ii < 4; ++ii) {
    int idx = tid + ii * 256;
    int row = idx >> 6, d = idx & 63;
    float m0 = mlds[0][row], m1 = mlds[1][row], m2 = mlds[2][row], m3 = mlds[3][row];
    float M = fmaxf(fmaxf(m0, m1), fmaxf(m2, m3));
    float f0 = exp2f(m0 - M), f1 = exp2f(m1 - M);
    float f2 = exp2f(m2 - M), f3 = exp2f(m3 - M);
    float L = llds[0][row] * f0 + llds[1][row] * f1 + llds[2][row] * f2 + llds[3][row] * f3;
    float O = Olds[0][row][d] * f0 + Olds[1][row][d] * f1 + Olds[2][row][d] * f2 + Olds[3][row][d] * f3;
    out[((size_t)b * 4096 + q0 + row) * 64 + d] = O / L;
  }
}

extern "C" void kernel_launch(void* const* d_in, const int* in_sizes, int n_in,
                              void* d_out, int out_size, void* d_ws, size_t ws_size,
                              hipStream_t stream) {
  const float* x = (const float*)d_in[0];
  const float* Wq = (const float*)d_in[1];
  const float* Wk = (const float*)d_in[2];
  const float* Wv = (const float*)d_in[3];
  float* out = (float*)d_out;

  char* ws = (char*)d_ws;
  unsigned short* Wt = (unsigned short*)ws;                  // 3*64*1024 bf16 = 384 KiB
  unsigned short* qm = (unsigned short*)(ws + 0x60000);      // 16384*64 bf16 = 2 MiB
  unsigned short* km = qm + (size_t)16384 * 64;              // 2 MiB
  unsigned short* vt = km + (size_t)16384 * 64;              // [4][64][4096] bf16 = 2 MiB

  wt_kernel<<<dim3(768), dim3(256), 0, stream>>>(Wq, Wk, Wv, Wt);
  proj_kernel<<<dim3(256), dim3(256), 0, stream>>>(x, Wt, qm, km, vt);
  attn_kernel<<<dim3(1024), dim3(256), 0, stream>>>(qm, km, vt, out);
}

// Round 2
// 138.217 us; speedup vs baseline: 1.3421x; 1.3421x over previous
//
#include <hip/hip_runtime.h>

typedef short s16x8 __attribute__((ext_vector_type(8)));
typedef float f32x4 __attribute__((ext_vector_type(4)));

#define MFMA(a, b, c) __builtin_amdgcn_mfma_f32_16x16x32_bf16(a, b, c, 0, 0, 0)

__device__ __forceinline__ unsigned short f2bf(float f) {
  unsigned int u = __builtin_bit_cast(unsigned int, f);
  u += 0x7FFFu + ((u >> 16) & 1u);
  return (unsigned short)(u >> 16);
}

// ---------- kernel 1: W [1024][64] fp32 -> Wt [3][64][1024] bf16 ----------
__global__ __launch_bounds__(256) void wt_kernel(const float* __restrict__ Wq,
                                                 const float* __restrict__ Wk,
                                                 const float* __restrict__ Wv,
                                                 unsigned short* __restrict__ Wt) {
  int i = blockIdx.x * 256 + threadIdx.x;  // 3*64*1024 = 196608 total
  int m = i >> 16;
  int rem = i & 65535;
  int h = rem >> 10;
  int c = rem & 1023;
  const float* W = (m == 0) ? Wq : (m == 1) ? Wk : Wv;
  Wt[i] = f2bf(W[c * 64 + h]);
}

// ---------- kernel 2: projection, K-split across 8 waves per block ----------
// block = 512 threads = 8 waves, all on the SAME 16-row tile of x.
// wave wv owns K range [wv*128, wv*128+128) (4 MFMA steps), partials reduced
// through LDS in 3 phases (one per output matrix).
__global__ __launch_bounds__(512) void proj_kernel(const float* __restrict__ x,
                                                   const unsigned short* __restrict__ Wt,
                                                   unsigned short* __restrict__ qm,
                                                   unsigned short* __restrict__ km,
                                                   unsigned short* __restrict__ vt) {
  __shared__ float red[8][4][16][16];  // 32 KiB

  int tid = threadIdx.x;
  int lane = tid & 63;
  int wv = tid >> 6;
  int row0 = blockIdx.x * 16;
  int c = lane & 15, g = lane >> 4;
  const float* xp = x + (size_t)(row0 + c) * 1024 + 8 * g;

  f32x4 acc[3][4];
#pragma unroll
  for (int m = 0; m < 3; ++m)
#pragma unroll
    for (int n = 0; n < 4; ++n) acc[m][n] = (f32x4){0.f, 0.f, 0.f, 0.f};

  int kbase = wv * 128;
#pragma unroll
  for (int it = 0; it < 4; ++it) {
    int k0 = kbase + it * 32;
    const float4* ap = (const float4*)(xp + k0);
    float4 a0 = ap[0], a1 = ap[1];
    s16x8 af;
    af[0] = (short)f2bf(a0.x); af[1] = (short)f2bf(a0.y);
    af[2] = (short)f2bf(a0.z); af[3] = (short)f2bf(a0.w);
    af[4] = (short)f2bf(a1.x); af[5] = (short)f2bf(a1.y);
    af[6] = (short)f2bf(a1.z); af[7] = (short)f2bf(a1.w);
#pragma unroll
    for (int m = 0; m < 3; ++m) {
#pragma unroll
      for (int n = 0; n < 4; ++n) {
        s16x8 bf = *(const s16x8*)(Wt + (size_t)(m * 64 + 16 * n + c) * 1024 + k0 + 8 * g);
        acc[m][n] = MFMA(af, bf, acc[m][n]);
      }
    }
  }

  int b = row0 >> 12;
#pragma unroll
  for (int m = 0; m < 3; ++m) {
#pragma unroll
    for (int n = 0; n < 4; ++n)
#pragma unroll
      for (int r = 0; r < 4; ++r) red[wv][n][4 * g + r][c] = acc[m][n][r];
    __syncthreads();
#pragma unroll
    for (int ii = 0; ii < 2; ++ii) {
      int idx = ii * 512 + tid;  // 0..1023
      int n = idx >> 8, row = (idx >> 4) & 15, col = idx & 15;
      float s = 0.f;
#pragma unroll
      for (int w = 0; w < 8; ++w) s += red[w][n][row][col];
      unsigned short hv = f2bf(s);
      int grow = row0 + row;
      int gcol = 16 * n + col;
      if (m == 0) qm[(size_t)grow * 64 + gcol] = hv;
      else if (m == 1) km[(size_t)grow * 64 + gcol] = hv;
      else vt[((size_t)b * 64 + gcol) * 4096 + (grow & 4095)] = hv;
    }
    __syncthreads();
  }
}

// ---------- kernel 3: flash attention ----------
// block = 4 waves; each block owns one 16-row Q tile; waves split KV tiles strided;
// online-softmax partials merged through LDS at the end.
__global__ __launch_bounds__(256) void attn_kernel(const unsigned short* __restrict__ qm,
                                                   const unsigned short* __restrict__ km,
                                                   const unsigned short* __restrict__ vt,
                                                   float* __restrict__ out) {
  __shared__ __align__(16) unsigned short Plds[4][16][32];
  __shared__ float Olds[4][16][64];
  __shared__ float mlds[4][16];
  __shared__ float llds[4][16];

  int tid = threadIdx.x;
  int lane = tid & 63, wv = tid >> 6;
  int c = lane & 15, g = lane >> 4;
  int bid = blockIdx.x;
  int b = bid & 3;
  int j = 255 - (bid >> 2);  // big tiles dispatched first
  int q0 = j * 16;
  int qlast = q0 + 15;
  const float SC = 0.1803368801111204f;  // (1/sqrt(64)) * log2(e)

  const unsigned short* qb = qm + ((size_t)b * 4096 + q0) * 64;
  s16x8 qf0 = *(const s16x8*)(qb + (size_t)c * 64 + 8 * g);
  s16x8 qf1 = *(const s16x8*)(qb + (size_t)c * 64 + 32 + 8 * g);

  f32x4 of[4];
#pragma unroll
  for (int d = 0; d < 4; ++d) of[d] = (f32x4){0.f, 0.f, 0.f, 0.f};
  float mrow[4] = {-1e30f, -1e30f, -1e30f, -1e30f};
  float lpart[4] = {0.f, 0.f, 0.f, 0.f};

  const unsigned short* kbb = km + (size_t)b * 4096 * 64;
  const unsigned short* vbb = vt + (size_t)b * 64 * 4096;

  for (int kv0 = wv * 32; kv0 <= qlast; kv0 += 128) {
    const unsigned short* kb = kbb + (size_t)kv0 * 64;
    s16x8 kf00 = *(const s16x8*)(kb + c * 64 + 8 * g);
    s16x8 kf01 = *(const s16x8*)(kb + c * 64 + 32 + 8 * g);
    s16x8 kf10 = *(const s16x8*)(kb + (16 + c) * 64 + 8 * g);
    s16x8 kf11 = *(const s16x8*)(kb + (16 + c) * 64 + 32 + 8 * g);

    f32x4 s0 = (f32x4){0.f, 0.f, 0.f, 0.f};
    f32x4 s1 = (f32x4){0.f, 0.f, 0.f, 0.f};
    s0 = MFMA(qf0, kf00, s0);
    s0 = MFMA(qf1, kf01, s0);
    s1 = MFMA(qf0, kf10, s1);
    s1 = MFMA(qf1, kf11, s1);

    float sv0[4], sv1[4], tm[4];
#pragma unroll
    for (int r = 0; r < 4; ++r) {
      int qr = q0 + 4 * g + r;
      float v0 = s0[r] * SC;
      if (kv0 + c > qr) v0 = -1e30f;
      float v1 = s1[r] * SC;
      if (kv0 + 16 + c > qr) v1 = -1e30f;
      sv0[r] = v0;
      sv1[r] = v1;
      tm[r] = fmaxf(v0, v1);
    }
#pragma unroll
    for (int msk = 1; msk <= 8; msk <<= 1) {
#pragma unroll
      for (int r = 0; r < 4; ++r) tm[r] = fmaxf(tm[r], __shfl_xor(tm[r], msk));
    }
    float p0[4], p1[4];
#pragma unroll
    for (int r = 0; r < 4; ++r) {
      float nm = fmaxf(mrow[r], tm[r]);
      float al = exp2f(mrow[r] - nm);
      mrow[r] = nm;
      p0[r] = exp2f(sv0[r] - nm);
      p1[r] = exp2f(sv1[r] - nm);
      lpart[r] = lpart[r] * al + p0[r] + p1[r];
      of[0][r] *= al;
      of[1][r] *= al;
      of[2][r] *= al;
      of[3][r] *= al;
    }
    // P -> LDS (S-layout) -> A-fragment layout
#pragma unroll
    for (int r = 0; r < 4; ++r) {
      Plds[wv][4 * g + r][c] = f2bf(p0[r]);
      Plds[wv][4 * g + r][16 + c] = f2bf(p1[r]);
    }
    s16x8 pf = *(const s16x8*)(&Plds[wv][c][8 * g]);
#pragma unroll
    for (int dt = 0; dt < 4; ++dt) {
      s16x8 vf = *(const s16x8*)(vbb + (size_t)(16 * dt + c) * 4096 + kv0 + 8 * g);
      of[dt] = MFMA(pf, vf, of[dt]);
    }
  }

  // ---- merge 4 wave-partials ----
  float lsum[4] = {lpart[0], lpart[1], lpart[2], lpart[3]};
#pragma unroll
  for (int msk = 1; msk <= 8; msk <<= 1) {
#pragma unroll
    for (int r = 0; r < 4; ++r) lsum[r] += __shfl_xor(lsum[r], msk);
  }
  if (c == 0) {
#pragma unroll
    for (int r = 0; r < 4; ++r) {
      mlds[wv][4 * g + r] = mrow[r];
      llds[wv][4 * g + r] = lsum[r];
    }
  }
#pragma unroll
  for (int dt = 0; dt < 4; ++dt)
#pragma unroll
    for (int r = 0; r < 4; ++r) Olds[wv][4 * g + r][16 * dt + c] = of[dt][r];
  __syncthreads();

#pragma unroll
  for (int ii = 0; ii < 4; ++ii) {
    int idx = tid + ii * 256;
    int row = idx >> 6, d = idx & 63;
    float m0 = mlds[0][row], m1 = mlds[1][row], m2 = mlds[2][row], m3 = mlds[3][row];
    float M = fmaxf(fmaxf(m0, m1), fmaxf(m2, m3));
    float f0 = exp2f(m0 - M), f1 = exp2f(m1 - M);
    float f2 = exp2f(m2 - M), f3 = exp2f(m3 - M);
    float L = llds[0][row] * f0 + llds[1][row] * f1 + llds[2][row] * f2 + llds[3][row] * f3;
    float O = Olds[0][row][d] * f0 + Olds[1][row][d] * f1 + Olds[2][row][d] * f2 + Olds[3][row][d] * f3;
    out[((size_t)b * 4096 + q0 + row) * 64 + d] = O / L;
  }
}

extern "C" void kernel_launch(void* const* d_in, const int* in_sizes, int n_in,
                              void* d_out, int out_size, void* d_ws, size_t ws_size,
                              hipStream_t stream) {
  const float* x = (const float*)d_in[0];
  const float* Wq = (const float*)d_in[1];
  const float* Wk = (const float*)d_in[2];
  const float* Wv = (const float*)d_in[3];
  float* out = (float*)d_out;

  char* ws = (char*)d_ws;
  unsigned short* Wt = (unsigned short*)ws;                  // 3*64*1024 bf16 = 384 KiB
  unsigned short* qm = (unsigned short*)(ws + 0x60000);      // 16384*64 bf16 = 2 MiB
  unsigned short* km = qm + (size_t)16384 * 64;              // 2 MiB
  unsigned short* vt = km + (size_t)16384 * 64;              // [4][64][4096] bf16 = 2 MiB

  wt_kernel<<<dim3(768), dim3(256), 0, stream>>>(Wq, Wk, Wv, Wt);
  proj_kernel<<<dim3(1024), dim3(512), 0, stream>>>(x, Wt, qm, km, vt);
  attn_kernel<<<dim3(1024), dim3(256), 0, stream>>>(qm, km, vt, out);
}

// Round 3
// 111.587 us; speedup vs baseline: 1.6624x; 1.2386x over previous
//
#include <hip/hip_runtime.h>

typedef short s16x8 __attribute__((ext_vector_type(8)));
typedef float f32x4 __attribute__((ext_vector_type(4)));
typedef float f32x16 __attribute__((ext_vector_type(16)));
typedef unsigned int u32x4 __attribute__((ext_vector_type(4)));

#define MFMA16(a, b, c) __builtin_amdgcn_mfma_f32_16x16x32_bf16(a, b, c, 0, 0, 0)
#define MFMA32(a, b, c) __builtin_amdgcn_mfma_f32_32x32x16_bf16(a, b, c, 0, 0, 0)

__device__ __forceinline__ unsigned short f2bf(float f) {
  unsigned int u = __builtin_bit_cast(unsigned int, f);
  u += 0x7FFFu + ((u >> 16) & 1u);
  return (unsigned short)(u >> 16);
}

__device__ __forceinline__ unsigned cvtpk(float lo, float hi) {
  unsigned r;
  asm("v_cvt_pk_bf16_f32 %0, %1, %2" : "=v"(r) : "v"(lo), "v"(hi));
  return r;
}

// vdst' = (vdst.lo, vsrc.lo); vsrc' = (vdst.hi, vsrc.hi)
__device__ __forceinline__ void plswap(unsigned& a, unsigned& b) {
  asm("v_permlane32_swap_b32 %0, %1" : "+v"(a), "+v"(b));
}

// ---------- kernel 1: W [1024][64] fp32 -> Wt [3][64][1024] bf16 ----------
__global__ __launch_bounds__(256) void wt_kernel(const float* __restrict__ Wq,
                                                 const float* __restrict__ Wk,
                                                 const float* __restrict__ Wv,
                                                 unsigned short* __restrict__ Wt) {
  int i = blockIdx.x * 256 + threadIdx.x;  // 3*64*1024 = 196608 total
  int m = i >> 16;
  int rem = i & 65535;
  int h = rem >> 10;
  int c = rem & 1023;
  const float* W = (m == 0) ? Wq : (m == 1) ? Wk : Wv;
  Wt[i] = f2bf(W[c * 64 + h]);
}

// ---------- kernel 2: projection, K-split across 8 waves per block ----------
__global__ __launch_bounds__(512) void proj_kernel(const float* __restrict__ x,
                                                   const unsigned short* __restrict__ Wt,
                                                   unsigned short* __restrict__ qm,
                                                   unsigned short* __restrict__ km,
                                                   unsigned short* __restrict__ vt) {
  __shared__ float red[8][4][16][16];  // 32 KiB

  int tid = threadIdx.x;
  int lane = tid & 63;
  int wv = tid >> 6;
  int row0 = blockIdx.x * 16;
  int c = lane & 15, g = lane >> 4;
  const float* xp = x + (size_t)(row0 + c) * 1024 + 8 * g;

  f32x4 acc[3][4];
#pragma unroll
  for (int m = 0; m < 3; ++m)
#pragma unroll
    for (int n = 0; n < 4; ++n) acc[m][n] = (f32x4){0.f, 0.f, 0.f, 0.f};

  int kbase = wv * 128;
#pragma unroll
  for (int it = 0; it < 4; ++it) {
    int k0 = kbase + it * 32;
    const float4* ap = (const float4*)(xp + k0);
    float4 a0 = ap[0], a1 = ap[1];
    s16x8 af;
    af[0] = (short)f2bf(a0.x); af[1] = (short)f2bf(a0.y);
    af[2] = (short)f2bf(a0.z); af[3] = (short)f2bf(a0.w);
    af[4] = (short)f2bf(a1.x); af[5] = (short)f2bf(a1.y);
    af[6] = (short)f2bf(a1.z); af[7] = (short)f2bf(a1.w);
#pragma unroll
    for (int m = 0; m < 3; ++m) {
#pragma unroll
      for (int n = 0; n < 4; ++n) {
        s16x8 bf = *(const s16x8*)(Wt + (size_t)(m * 64 + 16 * n + c) * 1024 + k0 + 8 * g);
        acc[m][n] = MFMA16(af, bf, acc[m][n]);
      }
    }
  }

  int b = row0 >> 12;
#pragma unroll
  for (int m = 0; m < 3; ++m) {
#pragma unroll
    for (int n = 0; n < 4; ++n)
#pragma unroll
      for (int r = 0; r < 4; ++r) red[wv][n][4 * g + r][c] = acc[m][n][r];
    __syncthreads();
#pragma unroll
    for (int ii = 0; ii < 2; ++ii) {
      int idx = ii * 512 + tid;  // 0..1023
      int n = idx >> 8, row = (idx >> 4) & 15, col = idx & 15;
      float s = 0.f;
#pragma unroll
      for (int w = 0; w < 8; ++w) s += red[w][n][row][col];
      unsigned short hv = f2bf(s);
      int grow = row0 + row;
      int gcol = 16 * n + col;
      if (m == 0) qm[(size_t)grow * 64 + gcol] = hv;
      else if (m == 1) km[(size_t)grow * 64 + gcol] = hv;
      else vt[((size_t)b * 64 + gcol) * 4096 + (grow & 4095)] = hv;
    }
    __syncthreads();
  }
}

// ---------- kernel 3: flash attention, swapped-QK^T 32x32 structure ----------
// 512 blocks = (b, Q-tile j of 32 rows), big tiles first. 8 waves/block split
// the KV range (stride 8*32); one wave handles the masked diagonal tile.
// S^T = mfma(K, Q): q = lane&31, kv in regs -> softmax nearly lane-local.
// P -> bf16 A-fragment via v_cvt_pk_bf16_f32 + v_permlane32_swap (no LDS).
__global__ __launch_bounds__(512) void attn_kernel(const unsigned short* __restrict__ qm,
                                                   const unsigned short* __restrict__ km,
                                                   const unsigned short* __restrict__ vt,
                                                   float* __restrict__ out) {
  __shared__ float Olds[4][32][64];  // 32 KiB, used in 2 phases (waves 0-3, 4-7)
  __shared__ float mlds[8][32];
  __shared__ float llds[8][32];
  __shared__ float flds[8][32];

  int tid = threadIdx.x;
  int lane = tid & 63, wv = tid >> 6;
  int ln = lane & 31, hi = lane >> 5;
  int bid = blockIdx.x;
  int b = bid & 3;
  int j = 127 - (bid >> 2);  // big Q-tiles dispatched first
  int q0 = j * 32;
  const float SC = 0.1803368801111204f;  // (1/sqrt(64)) * log2(e)

  // Q fragments (B-operand), hoisted: row q0+ln, k = 16*ks + 8*hi + [0..7]
  const unsigned short* qb = qm + ((size_t)b * 4096 + q0 + ln) * 64 + 8 * hi;
  s16x8 qf0 = *(const s16x8*)(qb);
  s16x8 qf1 = *(const s16x8*)(qb + 16);
  s16x8 qf2 = *(const s16x8*)(qb + 32);
  s16x8 qf3 = *(const s16x8*)(qb + 48);

  const unsigned short* kbb = km + (size_t)b * 4096 * 64 + (size_t)ln * 64 + 8 * hi;
  const unsigned short* vbb = vt + (size_t)b * 64 * 4096 + (size_t)ln * 4096 + 8 * hi;

  f32x16 of0 = {0.f, 0.f, 0.f, 0.f, 0.f, 0.f, 0.f, 0.f,
                0.f, 0.f, 0.f, 0.f, 0.f, 0.f, 0.f, 0.f};
  f32x16 of1 = of0;
  float mrow = -1e30f;
  float l = 0.f;

  auto process = [&](int kv0, bool diag) {
    const unsigned short* kp = kbb + (size_t)kv0 * 64;
    s16x8 kf0 = *(const s16x8*)(kp);
    s16x8 kf1 = *(const s16x8*)(kp + 16);
    s16x8 kf2 = *(const s16x8*)(kp + 32);
    s16x8 kf3 = *(const s16x8*)(kp + 48);
    f32x16 s = {0.f, 0.f, 0.f, 0.f, 0.f, 0.f, 0.f, 0.f,
                0.f, 0.f, 0.f, 0.f, 0.f, 0.f, 0.f, 0.f};
    __builtin_amdgcn_s_setprio(1);
    s = MFMA32(kf0, qf0, s);
    s = MFMA32(kf1, qf1, s);
    s = MFMA32(kf2, qf2, s);
    s = MFMA32(kf3, qf3, s);
    __builtin_amdgcn_s_setprio(0);

    float p[16];
#pragma unroll
    for (int r = 0; r < 16; ++r) p[r] = s[r] * SC;
    if (diag) {
#pragma unroll
      for (int r = 0; r < 16; ++r) {
        int kvr = (r & 3) + 8 * (r >> 2) + 4 * hi;
        if (kvr > ln) p[r] = -1e30f;
      }
    }
    float tmax = fmaxf(p[0], p[1]);
#pragma unroll
    for (int r = 2; r < 16; ++r) tmax = fmaxf(tmax, p[r]);
    tmax = fmaxf(tmax, __shfl_xor(tmax, 32));
    // T13 defer-max: only rescale when the running max grows materially
    if (!__all(tmax <= mrow + 8.0f)) {
      float nm = fmaxf(mrow, tmax);
      float al = __builtin_amdgcn_exp2f(mrow - nm);
      mrow = nm;
      l *= al;
#pragma unroll
      for (int r = 0; r < 16; ++r) { of0[r] *= al; of1[r] *= al; }
    }
    float lp = 0.f;
#pragma unroll
    for (int r = 0; r < 16; ++r) {
      p[r] = __builtin_amdgcn_exp2f(p[r] - mrow);
      lp += p[r];
    }
    lp += __shfl_xor(lp, 32);
    l += lp;

    // P -> bf16 A-fragments (T12): 8 cvt_pk + 4 permlane32_swap, no LDS
    u32x4 w0, w1;
    {
      unsigned x0 = cvtpk(p[0], p[1]), y0 = cvtpk(p[4], p[5]);
      plswap(x0, y0);
      unsigned x1 = cvtpk(p[2], p[3]), y1 = cvtpk(p[6], p[7]);
      plswap(x1, y1);
      w0[0] = x0; w0[1] = x1; w0[2] = y0; w0[3] = y1;
      unsigned x2 = cvtpk(p[8], p[9]), y2 = cvtpk(p[12], p[13]);
      plswap(x2, y2);
      unsigned x3 = cvtpk(p[10], p[11]), y3 = cvtpk(p[14], p[15]);
      plswap(x3, y3);
      w1[0] = x2; w1[1] = x3; w1[2] = y2; w1[3] = y3;
    }
    s16x8 pa0 = __builtin_bit_cast(s16x8, w0);
    s16x8 pa1 = __builtin_bit_cast(s16x8, w1);

    // PV: B = V[kv][d] from vt (d-major), kv slices of 16
    const unsigned short* vp = vbb + kv0;
    s16x8 vf00 = *(const s16x8*)(vp);
    s16x8 vf01 = *(const s16x8*)(vp + 16);
    s16x8 vf10 = *(const s16x8*)(vp + 32 * 4096);
    s16x8 vf11 = *(const s16x8*)(vp + 32 * 4096 + 16);
    __builtin_amdgcn_s_setprio(1);
    of0 = MFMA32(pa0, vf00, of0);
    of0 = MFMA32(pa1, vf01, of0);
    of1 = MFMA32(pa0, vf10, of1);
    of1 = MFMA32(pa1, vf11, of1);
    __builtin_amdgcn_s_setprio(0);
  };

  for (int t = wv; t < j; t += 8) process(t * 32, false);
  if (wv == (j & 7)) process(q0, true);

  if (hi == 0) {
    mlds[wv][ln] = mrow;
    llds[wv][ln] = l;
  }
  __syncthreads();

  // per-row merge factors f_w / L
  if (tid < 32) {
    int row = tid;
    float M = mlds[0][row];
#pragma unroll
    for (int w = 1; w < 8; ++w) M = fmaxf(M, mlds[w][row]);
    float L = 0.f, f[8];
#pragma unroll
    for (int w = 0; w < 8; ++w) {
      f[w] = __builtin_amdgcn_exp2f(mlds[w][row] - M);
      L += llds[w][row] * f[w];
    }
    float rL = 1.0f / L;
#pragma unroll
    for (int w = 0; w < 8; ++w) flds[w][row] = f[w] * rL;
  }

  // phase 1: waves 0-3 publish O partials
  if (wv < 4) {
#pragma unroll
    for (int r = 0; r < 16; ++r) {
      int qr = (r & 3) + 8 * (r >> 2) + 4 * hi;
      Olds[wv][qr][ln] = of0[r];
      Olds[wv][qr][32 + ln] = of1[r];
    }
  }
  __syncthreads();

  float accv[4];
#pragma unroll
  for (int ii = 0; ii < 4; ++ii) {
    int idx = ii * 512 + tid;
    int row = idx >> 6, d = idx & 63;
    float a = 0.f;
#pragma unroll
    for (int w = 0; w < 4; ++w) a += Olds[w][row][d] * flds[w][row];
    accv[ii] = a;
  }
  __syncthreads();

  // phase 2: waves 4-7 publish
  if (wv >= 4) {
#pragma unroll
    for (int r = 0; r < 16; ++r) {
      int qr = (r & 3) + 8 * (r >> 2) + 4 * hi;
      Olds[wv - 4][qr][ln] = of0[r];
      Olds[wv - 4][qr][32 + ln] = of1[r];
    }
  }
  __syncthreads();

#pragma unroll
  for (int ii = 0; ii < 4; ++ii) {
    int idx = ii * 512 + tid;
    int row = idx >> 6, d = idx & 63;
    float a = accv[ii];
#pragma unroll
    for (int w = 0; w < 4; ++w) a += Olds[w][row][d] * flds[w + 4][row];
    out[((size_t)b * 4096 + q0 + row) * 64 + d] = a;
  }
}

extern "C" void kernel_launch(void* const* d_in, const int* in_sizes, int n_in,
                              void* d_out, int out_size, void* d_ws, size_t ws_size,
                              hipStream_t stream) {
  const float* x = (const float*)d_in[0];
  const float* Wq = (const float*)d_in[1];
  const float* Wk = (const float*)d_in[2];
  const float* Wv = (const float*)d_in[3];
  float* out = (float*)d_out;

  char* ws = (char*)d_ws;
  unsigned short* Wt = (unsigned short*)ws;                  // 384 KiB
  unsigned short* qm = (unsigned short*)(ws + 0x60000);      // 2 MiB
  unsigned short* km = qm + (size_t)16384 * 64;              // 2 MiB
  unsigned short* vt = km + (size_t)16384 * 64;              // [4][64][4096] bf16

  wt_kernel<<<dim3(768), dim3(256), 0, stream>>>(Wq, Wk, Wv, Wt);
  proj_kernel<<<dim3(1024), dim3(512), 0, stream>>>(x, Wt, qm, km, vt);
  attn_kernel<<<dim3(512), dim3(512), 0, stream>>>(qm, km, vt, out);
}

// Round 4
// 106.024 us; speedup vs baseline: 1.7496x; 1.0525x over previous
//
#include <hip/hip_runtime.h>

typedef short s16x8 __attribute__((ext_vector_type(8)));
typedef float f32x4 __attribute__((ext_vector_type(4)));
typedef float f32x16 __attribute__((ext_vector_type(16)));
typedef unsigned int u32x4 __attribute__((ext_vector_type(4)));

#define MFMA16(a, b, c) __builtin_amdgcn_mfma_f32_16x16x32_bf16(a, b, c, 0, 0, 0)
#define MFMA32(a, b, c) __builtin_amdgcn_mfma_f32_32x32x16_bf16(a, b, c, 0, 0, 0)

__device__ __forceinline__ unsigned short f2bf(float f) {
  unsigned int u = __builtin_bit_cast(unsigned int, f);
  u += 0x7FFFu + ((u >> 16) & 1u);
  return (unsigned short)(u >> 16);
}

__device__ __forceinline__ unsigned cvtpk(float lo, float hi) {
  unsigned r;
  asm("v_cvt_pk_bf16_f32 %0, %1, %2" : "=v"(r) : "v"(lo), "v"(hi));
  return r;
}

// vdst' = (vdst.lo, vsrc.lo); vsrc' = (vdst.hi, vsrc.hi)
__device__ __forceinline__ void plswap(unsigned& a, unsigned& b) {
  asm("v_permlane32_swap_b32 %0, %1" : "+v"(a), "+v"(b));
}

// ---------- kernel 1: W [1024][64] fp32 -> Wt [3][64][1024] bf16 ----------
__global__ __launch_bounds__(256) void wt_kernel(const float* __restrict__ Wq,
                                                 const float* __restrict__ Wk,
                                                 const float* __restrict__ Wv,
                                                 unsigned short* __restrict__ Wt) {
  int i = blockIdx.x * 256 + threadIdx.x;  // 3*64*1024 = 196608 total
  int m = i >> 16;
  int rem = i & 65535;
  int h = rem >> 10;
  int c = rem & 1023;
  const float* W = (m == 0) ? Wq : (m == 1) ? Wk : Wv;
  Wt[i] = f2bf(W[c * 64 + h]);
}

// ---------- kernel 2: projection, LDS-staged GEMM [16384x1024]@[1024x192] ----------
// 1024 blocks x 256 thr (4 waves). Tile: 16 rows x 192 cols (full N), K-loop BK=64,
// double-buffered global_load_lds staging of the x slab (fp32), XOR-swizzled in 16B
// chunks (linear LDS dest + inverse-swizzled per-lane GLOBAL source + swizzled read).
// Wave wv owns combined cols [48wv, 48wv+48). No K-split -> no reduction phase.
__global__ __launch_bounds__(256) void proj_kernel(const float* __restrict__ x,
                                                   const unsigned short* __restrict__ Wt,
                                                   unsigned short* __restrict__ qm,
                                                   unsigned short* __restrict__ km,
                                                   unsigned short* __restrict__ vt) {
  __shared__ float xb[2][16 * 64];  // 2 x 4 KiB, linear layout for global_load_lds

  int tid = threadIdx.x;
  int lane = tid & 63, wv = tid >> 6;
  int c = lane & 15, g = lane >> 4;
  int row0 = blockIdx.x * 16;
  int b = row0 >> 12;

  // staging: thread tid fills 16B chunk #tid of the buffer (dest slot cs of row srow);
  // source chunk is cs ^ (srow&7) so that slot s holds logical chunk s ^ (row&7).
  int srow = tid >> 4;
  int scs = tid & 15;
  int schunk = scs ^ (srow & 7);
  const float* sbase = x + (size_t)(row0 + srow) * 1024 + schunk * 4;

  f32x4 acc[3];
  acc[0] = (f32x4){0.f, 0.f, 0.f, 0.f};
  acc[1] = acc[0];
  acc[2] = acc[0];

#define STAGE(buf, k0)                                                              \
  __builtin_amdgcn_global_load_lds(                                                 \
      (const __attribute__((address_space(1))) unsigned int*)(sbase + (k0)),        \
      (__attribute__((address_space(3))) unsigned int*)(&xb[buf][wv * 256]), 16, 0, 0)

  STAGE(0, 0);
  __syncthreads();

  for (int t = 0; t < 16; ++t) {
    if (t < 15) STAGE((t + 1) & 1, (t + 1) * 64);
    const float* xs = xb[t & 1];
    int k0 = t * 64;
#pragma unroll
    for (int kk = 0; kk < 2; ++kk) {
      // A fragment: row c, floats [32kk+8g, +8) -> swizzled chunks
      int s0 = (8 * kk + 2 * g) ^ (c & 7);
      int s1 = (8 * kk + 2 * g + 1) ^ (c & 7);
      f32x4 a0 = *(const f32x4*)(xs + c * 64 + s0 * 4);
      f32x4 a1 = *(const f32x4*)(xs + c * 64 + s1 * 4);
      s16x8 af;
      unsigned* au = (unsigned*)&af;
      au[0] = cvtpk(a0[0], a0[1]);
      au[1] = cvtpk(a0[2], a0[3]);
      au[2] = cvtpk(a1[0], a1[1]);
      au[3] = cvtpk(a1[2], a1[3]);
#pragma unroll
      for (int n = 0; n < 3; ++n) {
        int gcolc = 48 * wv + 16 * n + c;
        s16x8 bf = *(const s16x8*)(Wt + (size_t)gcolc * 1024 + k0 + 32 * kk + 8 * g);
        acc[n] = MFMA16(af, bf, acc[n]);
      }
    }
    __syncthreads();
  }
#undef STAGE

#pragma unroll
  for (int n = 0; n < 3; ++n) {
    int base = 48 * wv + 16 * n;  // 16-aligned, never straddles a 64-boundary
    int m = base >> 6;
    int gcolc = base + c;
    int h = gcolc & 63;
#pragma unroll
    for (int r = 0; r < 4; ++r) {
      unsigned short hv = f2bf(acc[n][r]);
      int grow = row0 + 4 * g + r;
      if (m == 0) qm[(size_t)grow * 64 + h] = hv;
      else if (m == 1) km[(size_t)grow * 64 + h] = hv;
      else vt[((size_t)b * 64 + h) * 4096 + (grow & 4095)] = hv;
    }
  }
}

// ---------- kernel 3: flash attention, swapped-QK^T 32x32 structure ----------
__global__ __launch_bounds__(512) void attn_kernel(const unsigned short* __restrict__ qm,
                                                   const unsigned short* __restrict__ km,
                                                   const unsigned short* __restrict__ vt,
                                                   float* __restrict__ out) {
  __shared__ float Olds[4][32][64];  // 32 KiB, used in 2 phases (waves 0-3, 4-7)
  __shared__ float mlds[8][32];
  __shared__ float llds[8][32];
  __shared__ float flds[8][32];

  int tid = threadIdx.x;
  int lane = tid & 63, wv = tid >> 6;
  int ln = lane & 31, hi = lane >> 5;
  int bid = blockIdx.x;
  int b = bid & 3;
  int j = 127 - (bid >> 2);  // big Q-tiles dispatched first
  int q0 = j * 32;
  const float SC = 0.1803368801111204f;  // (1/sqrt(64)) * log2(e)

  const unsigned short* qb = qm + ((size_t)b * 4096 + q0 + ln) * 64 + 8 * hi;
  s16x8 qf0 = *(const s16x8*)(qb);
  s16x8 qf1 = *(const s16x8*)(qb + 16);
  s16x8 qf2 = *(const s16x8*)(qb + 32);
  s16x8 qf3 = *(const s16x8*)(qb + 48);

  const unsigned short* kbb = km + (size_t)b * 4096 * 64 + (size_t)ln * 64 + 8 * hi;
  const unsigned short* vbb = vt + (size_t)b * 64 * 4096 + (size_t)ln * 4096 + 8 * hi;

  f32x16 of0 = {0.f, 0.f, 0.f, 0.f, 0.f, 0.f, 0.f, 0.f,
                0.f, 0.f, 0.f, 0.f, 0.f, 0.f, 0.f, 0.f};
  f32x16 of1 = of0;
  float mrow = -1e30f;
  float l = 0.f;

  auto process = [&](int kv0, bool diag) {
    const unsigned short* kp = kbb + (size_t)kv0 * 64;
    s16x8 kf0 = *(const s16x8*)(kp);
    s16x8 kf1 = *(const s16x8*)(kp + 16);
    s16x8 kf2 = *(const s16x8*)(kp + 32);
    s16x8 kf3 = *(const s16x8*)(kp + 48);
    f32x16 s = {0.f, 0.f, 0.f, 0.f, 0.f, 0.f, 0.f, 0.f,
                0.f, 0.f, 0.f, 0.f, 0.f, 0.f, 0.f, 0.f};
    __builtin_amdgcn_s_setprio(1);
    s = MFMA32(kf0, qf0, s);
    s = MFMA32(kf1, qf1, s);
    s = MFMA32(kf2, qf2, s);
    s = MFMA32(kf3, qf3, s);
    __builtin_amdgcn_s_setprio(0);

    float p[16];
#pragma unroll
    for (int r = 0; r < 16; ++r) p[r] = s[r] * SC;
    if (diag) {
#pragma unroll
      for (int r = 0; r < 16; ++r) {
        int kvr = (r & 3) + 8 * (r >> 2) + 4 * hi;
        if (kvr > ln) p[r] = -1e30f;
      }
    }
    float tmax = fmaxf(p[0], p[1]);
#pragma unroll
    for (int r = 2; r < 16; ++r) tmax = fmaxf(tmax, p[r]);
    tmax = fmaxf(tmax, __shfl_xor(tmax, 32));
    if (!__all(tmax <= mrow + 8.0f)) {
      float nm = fmaxf(mrow, tmax);
      float al = __builtin_amdgcn_exp2f(mrow - nm);
      mrow = nm;
      l *= al;
#pragma unroll
      for (int r = 0; r < 16; ++r) { of0[r] *= al; of1[r] *= al; }
    }
    float lp = 0.f;
#pragma unroll
    for (int r = 0; r < 16; ++r) {
      p[r] = __builtin_amdgcn_exp2f(p[r] - mrow);
      lp += p[r];
    }
    lp += __shfl_xor(lp, 32);
    l += lp;

    u32x4 w0, w1;
    {
      unsigned x0 = cvtpk(p[0], p[1]), y0 = cvtpk(p[4], p[5]);
      plswap(x0, y0);
      unsigned x1 = cvtpk(p[2], p[3]), y1 = cvtpk(p[6], p[7]);
      plswap(x1, y1);
      w0[0] = x0; w0[1] = x1; w0[2] = y0; w0[3] = y1;
      unsigned x2 = cvtpk(p[8], p[9]), y2 = cvtpk(p[12], p[13]);
      plswap(x2, y2);
      unsigned x3 = cvtpk(p[10], p[11]), y3 = cvtpk(p[14], p[15]);
      plswap(x3, y3);
      w1[0] = x2; w1[1] = x3; w1[2] = y2; w1[3] = y3;
    }
    s16x8 pa0 = __builtin_bit_cast(s16x8, w0);
    s16x8 pa1 = __builtin_bit_cast(s16x8, w1);

    const unsigned short* vp = vbb + kv0;
    s16x8 vf00 = *(const s16x8*)(vp);
    s16x8 vf01 = *(const s16x8*)(vp + 16);
    s16x8 vf10 = *(const s16x8*)(vp + 32 * 4096);
    s16x8 vf11 = *(const s16x8*)(vp + 32 * 4096 + 16);
    __builtin_amdgcn_s_setprio(1);
    of0 = MFMA32(pa0, vf00, of0);
    of0 = MFMA32(pa1, vf01, of0);
    of1 = MFMA32(pa0, vf10, of1);
    of1 = MFMA32(pa1, vf11, of1);
    __builtin_amdgcn_s_setprio(0);
  };

  for (int t = wv; t < j; t += 8) process(t * 32, false);
  if (wv == (j & 7)) process(q0, true);

  if (hi == 0) {
    mlds[wv][ln] = mrow;
    llds[wv][ln] = l;
  }
  __syncthreads();

  if (tid < 32) {
    int row = tid;
    float M = mlds[0][row];
#pragma unroll
    for (int w = 1; w < 8; ++w) M = fmaxf(M, mlds[w][row]);
    float L = 0.f, f[8];
#pragma unroll
    for (int w = 0; w < 8; ++w) {
      f[w] = __builtin_amdgcn_exp2f(mlds[w][row] - M);
      L += llds[w][row] * f[w];
    }
    float rL = 1.0f / L;
#pragma unroll
    for (int w = 0; w < 8; ++w) flds[w][row] = f[w] * rL;
  }

  if (wv < 4) {
#pragma unroll
    for (int r = 0; r < 16; ++r) {
      int qr = (r & 3) + 8 * (r >> 2) + 4 * hi;
      Olds[wv][qr][ln] = of0[r];
      Olds[wv][qr][32 + ln] = of1[r];
    }
  }
  __syncthreads();

  float accv[4];
#pragma unroll
  for (int ii = 0; ii < 4; ++ii) {
    int idx = ii * 512 + tid;
    int row = idx >> 6, d = idx & 63;
    float a = 0.f;
#pragma unroll
    for (int w = 0; w < 4; ++w) a += Olds[w][row][d] * flds[w][row];
    accv[ii] = a;
  }
  __syncthreads();

  if (wv >= 4) {
#pragma unroll
    for (int r = 0; r < 16; ++r) {
      int qr = (r & 3) + 8 * (r >> 2) + 4 * hi;
      Olds[wv - 4][qr][ln] = of0[r];
      Olds[wv - 4][qr][32 + ln] = of1[r];
    }
  }
  __syncthreads();

#pragma unroll
  for (int ii = 0; ii < 4; ++ii) {
    int idx = ii * 512 + tid;
    int row = idx >> 6, d = idx & 63;
    float a = accv[ii];
#pragma unroll
    for (int w = 0; w < 4; ++w) a += Olds[w][row][d] * flds[w + 4][row];
    out[((size_t)b * 4096 + q0 + row) * 64 + d] = a;
  }
}

extern "C" void kernel_launch(void* const* d_in, const int* in_sizes, int n_in,
                              void* d_out, int out_size, void* d_ws, size_t ws_size,
                              hipStream_t stream) {
  const float* x = (const float*)d_in[0];
  const float* Wq = (const float*)d_in[1];
  const float* Wk = (const float*)d_in[2];
  const float* Wv = (const float*)d_in[3];
  float* out = (float*)d_out;

  char* ws = (char*)d_ws;
  unsigned short* Wt = (unsigned short*)ws;                  // 384 KiB
  unsigned short* qm = (unsigned short*)(ws + 0x60000);      // 2 MiB
  unsigned short* km = qm + (size_t)16384 * 64;              // 2 MiB
  unsigned short* vt = km + (size_t)16384 * 64;              // [4][64][4096] bf16

  wt_kernel<<<dim3(768), dim3(256), 0, stream>>>(Wq, Wk, Wv, Wt);
  proj_kernel<<<dim3(1024), dim3(256), 0, stream>>>(x, Wt, qm, km, vt);
  attn_kernel<<<dim3(512), dim3(512), 0, stream>>>(qm, km, vt, out);
}